// Round 9
// baseline (203.059 us; speedup 1.0000x reference)
//
#include <hip/hip_runtime.h>

// B=2, S=2048, D=1024, H=16, DK=DV=64. M = B*S = 4096.
// Reference reshape (B,S,H*DK)->(B,H,S,DK) is a raw reinterpret: chunk
// c = flat>>17 is "head" c, viewed as [2048][64].
//
// SESSION FINDINGS:
//  - __builtin_amdgcn_exp2f gave absmax~0.72 (R3,R6); __expf passes. Banned.
//  - Q pre-scaled by 0.125f (exact pow2) in QKV epilogue.
//  - PV via 16x16x16 MFMA regressed (R8); K=32 everywhere.
//  - R9: cp16+DBUF gemm regressed vs reg-prefetch (dbuf variant only!).
//  - ~6-7us per kernel boundary. fillBufferAligned 256MB ~42us = harness
//    workspace re-poison, not addressable. Kernel sum ~105us.
//  - R11 REGRESSED: 128-row q-blocks spilled. R13 REGRESSED: K direct from
//    global = VMEM latency on QK^T critical path; keep K in LDS.
//  - R14 (41.9us flash, 198.2 total): y->qb balance permutation -> every
//    stride-256 CU class gets exactly 34 tiles.
//  - R15-R17 tr_read ARC ABANDONED: mapping correct but 8x asm tr_read
//    per kk pins ~90 live regs -> scratch demotion (WRITE 120-167MB).
//    vtrans restored. DO NOT retry without different register schedule.
//  - R18: setprio on flash MFMA = null-to-negative (flash 41.9->44.1us).
//    Flash 4-wave structure at local ceiling; FROZEN at R14 form.
//  - R19 (this): GEMM moved to m97-style global_load_lds: SINGLE LDS
//    buffer, 2 barriers/K-step, async direct-to-LDS staging (distinct
//    from R9's failed dbuf variant; m97=874TF vs reg-staging 646 at
//    128^2/BK=32). Wave w stages rows w*32+[0,32); LDS dest linear
//    lane*16B == row-major [128][32] (16*(4*(i>>2)+(i&3))=16i).

typedef __attribute__((ext_vector_type(8))) __bf16 bf16x8;
typedef __attribute__((ext_vector_type(8))) unsigned short ushort8;
typedef __attribute__((ext_vector_type(4))) unsigned short u16x4;
typedef __attribute__((ext_vector_type(4))) float f32x4;
typedef __attribute__((ext_vector_type(4))) unsigned int u32x4;

static __device__ __forceinline__ unsigned short f2bf(float f) {
    unsigned u = __builtin_bit_cast(unsigned, f);
    u += 0x7fffu + ((u >> 16) & 1u);
    return (unsigned short)(u >> 16);
}

static __device__ __forceinline__ float bf2f(unsigned short u) {
    return __builtin_bit_cast(float, (unsigned)u << 16);
}

// pack two f32 -> one u32 holding (bf16(lo) | bf16(hi)<<16), RNE
static __device__ __forceinline__ unsigned cvt_pk_bf16(float lo, float hi) {
    unsigned r;
    asm("v_cvt_pk_bf16_f32 %0, %1, %2" : "=v"(r) : "v"(lo), "v"(hi));
    return r;
}

// async global->LDS, 16B per lane; lds dest must be wave-uniform base
// (HW writes base + lane*16).
static __device__ __forceinline__ void gload16(const unsigned short* g, unsigned short* l) {
    __builtin_amdgcn_global_load_lds(
        (const __attribute__((address_space(1))) void*)g,
        (__attribute__((address_space(3))) void*)l, 16, 0, 0);
}

// Fused prep: z<4 -> transpose+cast weight z into WT + z*2^20 ([n][k] bf16);
// z==4 -> cast x slab to bf16. Grid (16,16,5) x 256.
__global__ __launch_bounds__(256) void prep_kernel(
    const float* __restrict__ x,
    const float* __restrict__ Wq, const float* __restrict__ Wk,
    const float* __restrict__ Wv, const float* __restrict__ Wo,
    unsigned short* __restrict__ xb, unsigned short* __restrict__ WT)
{
    const int tid = threadIdx.x;
    const int z = blockIdx.z;
    if (z == 4) {
        const int bid = blockIdx.y * 16 + blockIdx.x;      // 0..255
        const int base = bid * 4096 + tid;
        #pragma unroll
        for (int it = 0; it < 16; it++) {
            int i = base + it * 256;
            float4 v = ((const float4*)x)[i];
            ushort4 o;
            o.x = f2bf(v.x); o.y = f2bf(v.y); o.z = f2bf(v.z); o.w = f2bf(v.w);
            ((ushort4*)xb)[i] = o;
        }
        return;
    }
    const float* src = (z == 0) ? Wq : (z == 1) ? Wk : (z == 2) ? Wv : Wo;
    unsigned short* dst = WT + ((size_t)z << 20);
    __shared__ __align__(16) unsigned short t[64 * 68];
    const int n0 = blockIdx.x * 64, k0 = blockIdx.y * 64;
    #pragma unroll
    for (int u = 0; u < 4; u++) {
        int e = u * 256 + tid;
        int r = e >> 4, c4 = (e & 15) * 4;
        float4 v = *(const float4*)(src + (k0 + r) * 1024 + n0 + c4);
        ushort4 o;
        o.x = f2bf(v.x); o.y = f2bf(v.y); o.z = f2bf(v.z); o.w = f2bf(v.w);
        *(ushort4*)(t + r * 68 + c4) = o;
    }
    __syncthreads();
    #pragma unroll
    for (int u = 0; u < 4; u++) {
        int e = u * 256 + tid;
        int rn = e >> 4, ck = (e & 15) * 4;
        ushort4 o;
        o.x = t[(ck + 0) * 68 + rn];
        o.y = t[(ck + 1) * 68 + rn];
        o.z = t[(ck + 2) * 68 + rn];
        o.w = t[(ck + 3) * 68 + rn];
        *(ushort4*)(dst + (n0 + rn) * 1024 + k0 + ck) = o;
    }
}

// Transpose bf16 V-projection [4096][1024] into per-chunk VT[ch][dv][pos].
__global__ __launch_bounds__(256) void vtrans_kernel(const unsigned short* __restrict__ V,
                                                     unsigned short* __restrict__ VT) {
    __shared__ __align__(16) unsigned short t[64 * 68];
    const int tid = threadIdx.x;
    const int p0 = blockIdx.x * 64;
    const long base = (long)blockIdx.y * 131072;
    #pragma unroll
    for (int u = 0; u < 2; u++) {
        int e = u * 256 + tid;
        int r = e >> 3, c8 = (e & 7) * 8;
        ushort8 v = *(const ushort8*)(V + base + (long)(p0 + r) * 64 + c8);
        *(ushort8*)(t + r * 68 + c8) = v;
    }
    __syncthreads();
    #pragma unroll
    for (int u = 0; u < 4; u++) {
        int e = u * 256 + tid;
        int dv = e >> 4, pk = (e & 15) * 4;
        ushort4 o;
        o.x = t[(pk + 0) * 68 + dv];
        o.y = t[(pk + 1) * 68 + dv];
        o.z = t[(pk + 2) * 68 + dv];
        o.w = t[(pk + 3) * 68 + dv];
        *(ushort4*)(VT + base + (long)dv * 2048 + p0 + pk) = o;
    }
}

// 128x128-tile GEMM, BK=32, 4 waves (2x2). m97 structure: single LDS
// buffer, global_load_lds staging, 2 barriers per K-iteration.
// mode 0 (QKV, N=3072): which = n0g>>10 selects outQ/outK/outV; Q scaled 0.125.
// mode 1 (out-proj, N=1024): outQ = bf16(acc + bias + resid).
__global__ __launch_bounds__(256, 3) void gemm_kernel(
    const unsigned short* __restrict__ A,
    const unsigned short* __restrict__ Bt,
    const float* __restrict__ b0, const float* __restrict__ b1, const float* __restrict__ b2,
    unsigned short* __restrict__ outQ, unsigned short* __restrict__ outK,
    unsigned short* __restrict__ outV,
    const float* __restrict__ resid, int mode)
{
    __shared__ __align__(16) unsigned short As[128 * 32];
    __shared__ __align__(16) unsigned short Bs[128 * 32];
    const int tid = threadIdx.x;
    const int lane = tid & 63, wave = tid >> 6;
    const int quad = lane >> 4, l16 = lane & 15;
    const int wm = wave >> 1, wn = wave & 1;
    const int row0 = blockIdx.y * 128, n0g = blockIdx.x * 128;

    // Wave w stages tile rows w*32+[0,32): two 16-row instructions each
    // for A and B. Per-lane global src; wave-uniform LDS base (linear).
    const int srow = wave * 32 + (lane >> 2);
    const int scol = (lane & 3) * 8;
    const unsigned short* Ag0 = A + (size_t)(row0 + srow) * 1024 + scol;
    const unsigned short* Ag1 = Ag0 + (size_t)16 * 1024;
    const unsigned short* Bg0 = Bt + (size_t)(n0g + srow) * 1024 + scol;
    const unsigned short* Bg1 = Bg0 + (size_t)16 * 1024;
    unsigned short* AsW = As + wave * 1024;   // byte offset wave*2048
    unsigned short* BsW = Bs + wave * 1024;

    gload16(Ag0, AsW);
    gload16(Ag1, AsW + 512);
    gload16(Bg0, BsW);
    gload16(Bg1, BsW + 512);
    __syncthreads();

    f32x4 acc[4][4] = {};
    for (int it = 0; it < 32; ++it) {
        bf16x8 af[4], bfr[4];
        #pragma unroll
        for (int i = 0; i < 4; i++)
            af[i] = *(const bf16x8*)(As + (wm * 64 + i * 16 + l16) * 32 + quad * 8);
        #pragma unroll
        for (int j = 0; j < 4; j++)
            bfr[j] = *(const bf16x8*)(Bs + (wn * 64 + j * 16 + l16) * 32 + quad * 8);
        #pragma unroll
        for (int i = 0; i < 4; i++)
            #pragma unroll
            for (int j = 0; j < 4; j++)
                acc[i][j] = __builtin_amdgcn_mfma_f32_16x16x32_bf16(af[i], bfr[j], acc[i][j], 0, 0, 0);
        if (it < 31) {
            __syncthreads();   // all waves done reading As/Bs
            const int k0 = (it + 1) * 32;
            gload16(Ag0 + k0, AsW);
            gload16(Ag1 + k0, AsW + 512);
            gload16(Bg0 + k0, BsW);
            gload16(Bg1 + k0, BsW + 512);
            __syncthreads();   // staging complete (vmcnt drained at barrier)
        }
    }

    if (mode == 0) {
        const int which = n0g >> 10;
        const float* bp = (which == 0) ? b0 : (which == 1) ? b1 : b2;
        unsigned short* op = (which == 0) ? outQ : (which == 1) ? outK : outV;
        const float scl = (which == 0) ? 0.125f : 1.0f;
        #pragma unroll
        for (int i = 0; i < 4; i++)
            #pragma unroll
            for (int j = 0; j < 4; j++) {
                int c = (n0g + wn * 64 + j * 16 + l16) & 1023;
                float bj = bp[c];
                #pragma unroll
                for (int r = 0; r < 4; r++) {
                    int r_g = row0 + wm * 64 + i * 16 + quad * 4 + r;
                    op[(size_t)r_g * 1024 + c] = f2bf((acc[i][j][r] + bj) * scl);
                }
            }
    } else {
        #pragma unroll
        for (int i = 0; i < 4; i++)
            #pragma unroll
            for (int j = 0; j < 4; j++) {
                int c_g = n0g + wn * 64 + j * 16 + l16;
                float bj = b0[c_g];
                #pragma unroll
                for (int r = 0; r < 4; r++) {
                    int r_g = row0 + wm * 64 + i * 16 + quad * 4 + r;
                    size_t idx = (size_t)r_g * 1024 + c_g;
                    outQ[idx] = f2bf(acc[i][j][r] + bj + resid[idx]);
                }
            }
    }
}

// Causal flash attention, S^T formulation, in-register P (no Pt LDS).
// R14-FROZEN: 64-row Q blocks, 4 waves x 16 q-rows, Kt+Vt LDS with
// register-prefetch dbuf, y->qb balance permutation (34 tiles/CU class).
// P redistribution quad-exchange (verified R11/R12):
//   cvt_pk_bf16 pairs (E from even c, O from odd c), then
//   permlane32_swap + permlane16_swap: (E0,O0)->(word0,word2),
//   (E1,O1)->(word1,word3).
__global__ __launch_bounds__(256, 4) void flash_kernel(
    const unsigned short* __restrict__ Q,
    const unsigned short* __restrict__ K,
    const unsigned short* __restrict__ VT,
    unsigned short* __restrict__ Ctx)
{
    __shared__ __align__(16) unsigned short Kt[128 * 72];    // [kpos][dk]
    __shared__ __align__(16) unsigned short Vt[64 * 136];    // [dv][kpos]
    const int tid = threadIdx.x;
    const int lane = tid & 63, wave = tid >> 6;
    const int quad = lane >> 4, l16 = lane & 15;
    const int y = blockIdx.y;
    const int qb = (y < 8) ? (31 - y) : (y < 16) ? (y - 8)
                 : (y < 24) ? (39 - y) : (y - 16);
    const int q0 = qb * 64;
    const long base = (long)blockIdx.x * 131072;
    const int nt = (qb + 2) >> 1;

    bf16x8 qa[2];
    #pragma unroll
    for (int h = 0; h < 2; h++)
        qa[h] = *(const bf16x8*)(Q + base + (q0 + wave * 16 + l16) * 64 + h * 32 + quad * 8);

    f32x4 o[4] = {};
    float l_one = 0.f;
    const int qpos = q0 + wave * 16 + l16;

    // stage tile 0
    #pragma unroll
    for (int u = 0; u < 4; u++) {
        int e = u * 256 + tid;
        int r = e >> 3, c = (e & 7) * 8;
        *(ushort8*)(Kt + r * 72 + c) = *(const ushort8*)(K + base + (long)r * 64 + c);
        int dv = e >> 4, kc = (e & 15) * 8;
        *(ushort8*)(Vt + dv * 136 + kc) = *(const ushort8*)(VT + base + (long)dv * 2048 + kc);
    }
    __syncthreads();

    for (int t = 0; t < nt; t++) {
        ushort8 nk[4], nv[4];
        if (t + 1 < nt) {
            const int k1 = (t + 1) * 128;
            #pragma unroll
            for (int u = 0; u < 4; u++) {
                int e = u * 256 + tid;
                int r = e >> 3, c = (e & 7) * 8;
                nk[u] = *(const ushort8*)(K + base + (long)(k1 + r) * 64 + c);
                int dv = e >> 4, kc = (e & 15) * 8;
                nv[u] = *(const ushort8*)(VT + base + (long)dv * 2048 + k1 + kc);
            }
        }
        const int k0 = t * 128;
        const bool diag = (t == nt - 1);
        // wave w needs kpos up to q0+16w+15; pairs kk<=kkmax.
        const int kkmax = diag ? ((q0 - k0 + wave * 16 + 15) >> 5) : 3;

        #pragma unroll
        for (int kk = 0; kk < 4; kk++) {
            if (kk <= kkmax) {
                const int cE = kk * 2, cO = kk * 2 + 1;
                f32x4 aE = {}, aO = {};
                {
                    bf16x8 kb0 = *(const bf16x8*)(Kt + (cE * 16 + l16) * 72 + quad * 8);
                    bf16x8 kb1 = *(const bf16x8*)(Kt + (cE * 16 + l16) * 72 + 32 + quad * 8);
                    aE = __builtin_amdgcn_mfma_f32_16x16x32_bf16(kb0, qa[0], aE, 0, 0, 0);
                    aE = __builtin_amdgcn_mfma_f32_16x16x32_bf16(kb1, qa[1], aE, 0, 0, 0);
                }
                {
                    bf16x8 kb0 = *(const bf16x8*)(Kt + (cO * 16 + l16) * 72 + quad * 8);
                    bf16x8 kb1 = *(const bf16x8*)(Kt + (cO * 16 + l16) * 72 + 32 + quad * 8);
                    aO = __builtin_amdgcn_mfma_f32_16x16x32_bf16(kb0, qa[0], aO, 0, 0, 0);
                    aO = __builtin_amdgcn_mfma_f32_16x16x32_bf16(kb1, qa[1], aO, 0, 0, 0);
                }
                float pE[4], pO[4];
                #pragma unroll
                for (int r = 0; r < 4; r++) {
                    float e1 = __expf(aE[r]);
                    float e2 = __expf(aO[r]);
                    if (diag) {
                        int kE = k0 + cE * 16 + quad * 4 + r;
                        int kO = k0 + cO * 16 + quad * 4 + r;
                        e1 = (kE > qpos) ? 0.f : e1;
                        e2 = (kO > qpos) ? 0.f : e2;
                    }
                    pE[r] = e1; pO[r] = e2;
                }
                l_one += (pE[0] + pE[1]) + (pE[2] + pE[3])
                       + (pO[0] + pO[1]) + (pO[2] + pO[3]);
                unsigned w0 = cvt_pk_bf16(pE[0], pE[1]);   // E0
                unsigned w1 = cvt_pk_bf16(pE[2], pE[3]);   // E1
                unsigned w2 = cvt_pk_bf16(pO[0], pO[1]);   // O0
                unsigned w3 = cvt_pk_bf16(pO[2], pO[3]);   // O1
                // (E0,O0) -> word0/word2 ; (E1,O1) -> word1/word3
                asm("v_permlane32_swap_b32 %0, %1" : "+v"(w0), "+v"(w2));
                asm("v_permlane16_swap_b32 %0, %1" : "+v"(w0), "+v"(w2));
                asm("v_permlane32_swap_b32 %0, %1" : "+v"(w1), "+v"(w3));
                asm("v_permlane16_swap_b32 %0, %1" : "+v"(w1), "+v"(w3));
                u32x4 pu;
                pu[0] = w0; pu[1] = w1; pu[2] = w2; pu[3] = w3;
                bf16x8 pa = __builtin_bit_cast(bf16x8, pu);
                #pragma unroll
                for (int c2 = 0; c2 < 4; c2++) {
                    bf16x8 vb = *(const bf16x8*)(Vt + (c2 * 16 + l16) * 136 + kk * 32 + quad * 8);
                    o[c2] = __builtin_amdgcn_mfma_f32_16x16x32_bf16(pa, vb, o[c2], 0, 0, 0);
                }
            }
        }
        __syncthreads();
        if (t + 1 < nt) {
            #pragma unroll
            for (int u = 0; u < 4; u++) {
                int e = u * 256 + tid;
                int r = e >> 3, c = (e & 7) * 8;
                *(ushort8*)(Kt + r * 72 + c) = nk[u];
                int dv = e >> 4, kc = (e & 15) * 8;
                *(ushort8*)(Vt + dv * 136 + kc) = nv[u];
            }
            __syncthreads();
        }
    }

    l_one += __shfl_xor(l_one, 16, 64);
    l_one += __shfl_xor(l_one, 32, 64);
    float rinv[4];
    #pragma unroll
    for (int r = 0; r < 4; r++)
        rinv[r] = 1.0f / __shfl(l_one, quad * 4 + r, 16);
    #pragma unroll
    for (int c2 = 0; c2 < 4; c2++)
        #pragma unroll
        for (int r = 0; r < 4; r++) {
            int row = q0 + wave * 16 + quad * 4 + r;
            Ctx[base + (long)row * 64 + c2 * 16 + l16] = f2bf(o[c2][r] * rinv[r]);
        }
}

// LayerNorm over bf16 input rows (out-proj+resid already applied), fp32 out.
__global__ __launch_bounds__(256) void ln_kernel(const unsigned short* __restrict__ inp,
                                                 const float* __restrict__ gamma,
                                                 const float* __restrict__ beta,
                                                 float* __restrict__ out)
{
    __shared__ float ssum[4], ssq[4];
    const int row = blockIdx.x;
    const int tid = threadIdx.x;
    ushort4 uv = ((const ushort4*)(inp + (size_t)row * 1024))[tid];
    float vx = bf2f(uv.x), vy = bf2f(uv.y), vz = bf2f(uv.z), vw = bf2f(uv.w);
    float s = vx + vy + vz + vw;
    float q = vx * vx + vy * vy + vz * vz + vw * vw;
    #pragma unroll
    for (int off = 32; off >= 1; off >>= 1) {
        s += __shfl_xor(s, off, 64);
        q += __shfl_xor(q, off, 64);
    }
    if ((tid & 63) == 0) { ssum[tid >> 6] = s; ssq[tid >> 6] = q; }
    __syncthreads();
    float ts = ssum[0] + ssum[1] + ssum[2] + ssum[3];
    float tq = ssq[0] + ssq[1] + ssq[2] + ssq[3];
    float mean = ts * (1.f / 1024.f);
    float var = tq * (1.f / 1024.f) - mean * mean;
    float rinv = rsqrtf(var + 1e-5f);
    float4 g = ((const float4*)gamma)[tid];
    float4 b = ((const float4*)beta)[tid];
    float4 o;
    o.x = (vx - mean) * rinv * g.x + b.x;
    o.y = (vy - mean) * rinv * g.y + b.y;
    o.z = (vz - mean) * rinv * g.z + b.z;
    o.w = (vw - mean) * rinv * g.w + b.w;
    ((float4*)(out + (size_t)row * 1024))[tid] = o;
}

extern "C" void kernel_launch(void* const* d_in, const int* in_sizes, int n_in,
                              void* d_out, int out_size, void* d_ws, size_t ws_size,
                              hipStream_t stream) {
    const float* x     = (const float*)d_in[0];
    const float* Wk    = (const float*)d_in[1];
    const float* bk    = (const float*)d_in[2];
    const float* Wq    = (const float*)d_in[3];
    const float* bq    = (const float*)d_in[4];
    const float* Wv    = (const float*)d_in[5];
    const float* bv    = (const float*)d_in[6];
    const float* Wo    = (const float*)d_in[7];
    const float* bo    = (const float*)d_in[8];
    const float* gamma = (const float*)d_in[9];
    const float* beta  = (const float*)d_in[10];
    float* out = (float*)d_out;

    char* ws = (char*)d_ws;
    unsigned short* xb    = (unsigned short*)(ws);                 // 8 MB
    unsigned short* WqkvT = (unsigned short*)(ws + (8ull << 20));  // 8 MB (incl WoT at +6MB)
    unsigned short* Qb    = (unsigned short*)(ws + (16ull << 20)); // 8 MB
    unsigned short* Kb    = (unsigned short*)(ws + (24ull << 20)); // 8 MB
    unsigned short* VbT   = (unsigned short*)(ws + (32ull << 20)); // 8 MB
    unsigned short* Cb    = (unsigned short*)(ws + (40ull << 20)); // 8 MB
    unsigned short* outp  = (unsigned short*)(ws + (48ull << 20)); // 8 MB bf16
    unsigned short* WoT   = WqkvT + (3u << 20);
    unsigned short* Vbn   = Cb;  // V normal layout, dead before flash writes Cb

    dim3 pgrid(16, 16, 5);
    prep_kernel<<<pgrid, 256, 0, stream>>>(x, Wq, Wk, Wv, Wo, xb, WqkvT);

    dim3 qkvgrid(24, 32);
    gemm_kernel<<<qkvgrid, 256, 0, stream>>>(xb, WqkvT, bq, bk, bv,
                                             Qb, Kb, Vbn, nullptr, 0);

    dim3 vgrid(32, 32);
    vtrans_kernel<<<vgrid, 256, 0, stream>>>(Vbn, VbT);

    dim3 fgrid(32, 32);
    flash_kernel<<<fgrid, 256, 0, stream>>>(Qb, Kb, VbT, Cb);

    dim3 ogrid(8, 32);
    gemm_kernel<<<ogrid, 256, 0, stream>>>(Cb, WoT, bo, nullptr, nullptr,
                                           outp, nullptr, nullptr, x, 1);

    ln_kernel<<<4096, 256, 0, stream>>>(outp, gamma, beta, out);
}

// Round 10
// 196.141 us; speedup vs baseline: 1.0353x; 1.0353x over previous
//
#include <hip/hip_runtime.h>

// B=2, S=2048, D=1024, H=16, DK=DV=64. M = B*S = 4096.
// Reference reshape (B,S,H*DK)->(B,H,S,DK) is a raw reinterpret: chunk
// c = flat>>17 is "head" c, viewed as [2048][64].
//
// SESSION FINDINGS (final):
//  - __builtin_amdgcn_exp2f gave absmax~0.72; __expf passes. Banned.
//  - Q pre-scaled by 0.125f (exact pow2) in QKV epilogue.
//  - PV via 16x16x16 MFMA regressed; K=32 everywhere.
//  - GEMM staging: reg-prefetch dbuf + 1 barrier/K-step is the winner.
//    Both alternatives measured worse: cp16+dbuf (R9-old), m97-style
//    global_load_lds single-buffer 2-barrier (R19: +5-8us at K=1024 —
//    the 2nd barrier's vmcnt drain isn't amortized at 32 K-steps).
//  - Budget: fills 2x256MB ~84us (harness re-poison, not addressable) +
//    kernels ~105us + boundaries ~7us (~1us each) = ~196us floor.
//  - R14 flash = ceiling for the 4-wave structure: y->qb balance
//    permutation (every stride-256 CU class = exactly 34 tiles),
//    in-register P via cvt_pk + permlane32/16_swap. T5 setprio tested
//    null-to-negative (R18); K-direct-from-global regressed (R13);
//    tr_read V-fusion abandoned (R15-17: correct mapping but asm-array
//    codegen demotes to scratch, WRITE 120-167MB).
//  - This file = R4/R14 configuration, the session's validated best
//    (198.2us; statistically tied best with R8's 197.1).

typedef __attribute__((ext_vector_type(8))) __bf16 bf16x8;
typedef __attribute__((ext_vector_type(8))) unsigned short ushort8;
typedef __attribute__((ext_vector_type(4))) unsigned short u16x4;
typedef __attribute__((ext_vector_type(4))) float f32x4;
typedef __attribute__((ext_vector_type(4))) unsigned int u32x4;

static __device__ __forceinline__ unsigned short f2bf(float f) {
    unsigned u = __builtin_bit_cast(unsigned, f);
    u += 0x7fffu + ((u >> 16) & 1u);
    return (unsigned short)(u >> 16);
}

static __device__ __forceinline__ float bf2f(unsigned short u) {
    return __builtin_bit_cast(float, (unsigned)u << 16);
}

// pack two f32 -> one u32 holding (bf16(lo) | bf16(hi)<<16), RNE
static __device__ __forceinline__ unsigned cvt_pk_bf16(float lo, float hi) {
    unsigned r;
    asm("v_cvt_pk_bf16_f32 %0, %1, %2" : "=v"(r) : "v"(lo), "v"(hi));
    return r;
}

// Fused prep: z<4 -> transpose+cast weight z into WT + z*2^20 ([n][k] bf16);
// z==4 -> cast x slab to bf16. Grid (16,16,5) x 256.
__global__ __launch_bounds__(256) void prep_kernel(
    const float* __restrict__ x,
    const float* __restrict__ Wq, const float* __restrict__ Wk,
    const float* __restrict__ Wv, const float* __restrict__ Wo,
    unsigned short* __restrict__ xb, unsigned short* __restrict__ WT)
{
    const int tid = threadIdx.x;
    const int z = blockIdx.z;
    if (z == 4) {
        const int bid = blockIdx.y * 16 + blockIdx.x;      // 0..255
        const int base = bid * 4096 + tid;
        #pragma unroll
        for (int it = 0; it < 16; it++) {
            int i = base + it * 256;
            float4 v = ((const float4*)x)[i];
            ushort4 o;
            o.x = f2bf(v.x); o.y = f2bf(v.y); o.z = f2bf(v.z); o.w = f2bf(v.w);
            ((ushort4*)xb)[i] = o;
        }
        return;
    }
    const float* src = (z == 0) ? Wq : (z == 1) ? Wk : (z == 2) ? Wv : Wo;
    unsigned short* dst = WT + ((size_t)z << 20);
    __shared__ __align__(16) unsigned short t[64 * 68];
    const int n0 = blockIdx.x * 64, k0 = blockIdx.y * 64;
    #pragma unroll
    for (int u = 0; u < 4; u++) {
        int e = u * 256 + tid;
        int r = e >> 4, c4 = (e & 15) * 4;
        float4 v = *(const float4*)(src + (k0 + r) * 1024 + n0 + c4);
        ushort4 o;
        o.x = f2bf(v.x); o.y = f2bf(v.y); o.z = f2bf(v.z); o.w = f2bf(v.w);
        *(ushort4*)(t + r * 68 + c4) = o;
    }
    __syncthreads();
    #pragma unroll
    for (int u = 0; u < 4; u++) {
        int e = u * 256 + tid;
        int rn = e >> 4, ck = (e & 15) * 4;
        ushort4 o;
        o.x = t[(ck + 0) * 68 + rn];
        o.y = t[(ck + 1) * 68 + rn];
        o.z = t[(ck + 2) * 68 + rn];
        o.w = t[(ck + 3) * 68 + rn];
        *(ushort4*)(dst + (n0 + rn) * 1024 + k0 + ck) = o;
    }
}

// Transpose bf16 V-projection [4096][1024] into per-chunk VT[ch][dv][pos].
__global__ __launch_bounds__(256) void vtrans_kernel(const unsigned short* __restrict__ V,
                                                     unsigned short* __restrict__ VT) {
    __shared__ __align__(16) unsigned short t[64 * 68];
    const int tid = threadIdx.x;
    const int p0 = blockIdx.x * 64;
    const long base = (long)blockIdx.y * 131072;
    #pragma unroll
    for (int u = 0; u < 2; u++) {
        int e = u * 256 + tid;
        int r = e >> 3, c8 = (e & 7) * 8;
        ushort8 v = *(const ushort8*)(V + base + (long)(p0 + r) * 64 + c8);
        *(ushort8*)(t + r * 68 + c8) = v;
    }
    __syncthreads();
    #pragma unroll
    for (int u = 0; u < 4; u++) {
        int e = u * 256 + tid;
        int dv = e >> 4, pk = (e & 15) * 4;
        ushort4 o;
        o.x = t[(pk + 0) * 68 + dv];
        o.y = t[(pk + 1) * 68 + dv];
        o.z = t[(pk + 2) * 68 + dv];
        o.w = t[(pk + 3) * 68 + dv];
        *(ushort4*)(VT + base + (long)dv * 2048 + p0 + pk) = o;
    }
}

// 128x128-tile GEMM, BK=32, 4 waves (2x2). Register-prefetch + dbuf LDS,
// one barrier per K-iteration (R7-proven, reconfirmed vs R19 gload_lds).
// mode 0 (QKV, N=3072): which = n0g>>10 selects outQ/outK/outV; Q scaled 0.125.
// mode 1 (out-proj, N=1024): outQ = bf16(acc + bias + resid).
__global__ __launch_bounds__(256, 3) void gemm_kernel(
    const unsigned short* __restrict__ A,
    const unsigned short* __restrict__ Bt,
    const float* __restrict__ b0, const float* __restrict__ b1, const float* __restrict__ b2,
    unsigned short* __restrict__ outQ, unsigned short* __restrict__ outK,
    unsigned short* __restrict__ outV,
    const float* __restrict__ resid, int mode)
{
    __shared__ __align__(16) unsigned short As[2][128 * 32];
    __shared__ __align__(16) unsigned short Bs[2][128 * 32];
    const int tid = threadIdx.x;
    const int lane = tid & 63, wave = tid >> 6;
    const int quad = lane >> 4, l16 = lane & 15;
    const int wm = wave >> 1, wn = wave & 1;
    const int row0 = blockIdx.y * 128, n0g = blockIdx.x * 128;

    const int sr = tid >> 2;
    const int sc = (tid & 3) * 8;
    const unsigned short* Ag0 = A + (size_t)(row0 + sr) * 1024 + sc;
    const unsigned short* Ag1 = A + (size_t)(row0 + 64 + sr) * 1024 + sc;
    const unsigned short* Bg0 = Bt + (size_t)(n0g + sr) * 1024 + sc;
    const unsigned short* Bg1 = Bt + (size_t)(n0g + 64 + sr) * 1024 + sc;

    {
        ushort8 a0 = *(const ushort8*)(Ag0);
        ushort8 a1 = *(const ushort8*)(Ag1);
        ushort8 bv0 = *(const ushort8*)(Bg0);
        ushort8 bv1 = *(const ushort8*)(Bg1);
        *(ushort8*)(As[0] + sr * 32 + sc) = a0;
        *(ushort8*)(As[0] + (64 + sr) * 32 + sc) = a1;
        *(ushort8*)(Bs[0] + sr * 32 + sc) = bv0;
        *(ushort8*)(Bs[0] + (64 + sr) * 32 + sc) = bv1;
    }
    __syncthreads();

    f32x4 acc[4][4] = {};
    #pragma unroll 2
    for (int it = 0; it < 32; ++it) {
        const int cur = it & 1;
        ushort8 na0, na1, nb0, nb1;
        if (it < 31) {
            const int k0 = (it + 1) * 32;
            na0 = *(const ushort8*)(Ag0 + k0);
            na1 = *(const ushort8*)(Ag1 + k0);
            nb0 = *(const ushort8*)(Bg0 + k0);
            nb1 = *(const ushort8*)(Bg1 + k0);
        }
        bf16x8 af[4], bfr[4];
        #pragma unroll
        for (int i = 0; i < 4; i++)
            af[i] = *(const bf16x8*)(As[cur] + (wm * 64 + i * 16 + l16) * 32 + quad * 8);
        #pragma unroll
        for (int j = 0; j < 4; j++)
            bfr[j] = *(const bf16x8*)(Bs[cur] + (wn * 64 + j * 16 + l16) * 32 + quad * 8);
        #pragma unroll
        for (int i = 0; i < 4; i++)
            #pragma unroll
            for (int j = 0; j < 4; j++)
                acc[i][j] = __builtin_amdgcn_mfma_f32_16x16x32_bf16(af[i], bfr[j], acc[i][j], 0, 0, 0);
        if (it < 31) {
            const int nxt = cur ^ 1;
            *(ushort8*)(As[nxt] + sr * 32 + sc) = na0;
            *(ushort8*)(As[nxt] + (64 + sr) * 32 + sc) = na1;
            *(ushort8*)(Bs[nxt] + sr * 32 + sc) = nb0;
            *(ushort8*)(Bs[nxt] + (64 + sr) * 32 + sc) = nb1;
            __syncthreads();
        }
    }

    if (mode == 0) {
        const int which = n0g >> 10;
        const float* bp = (which == 0) ? b0 : (which == 1) ? b1 : b2;
        unsigned short* op = (which == 0) ? outQ : (which == 1) ? outK : outV;
        const float scl = (which == 0) ? 0.125f : 1.0f;
        #pragma unroll
        for (int i = 0; i < 4; i++)
            #pragma unroll
            for (int j = 0; j < 4; j++) {
                int c = (n0g + wn * 64 + j * 16 + l16) & 1023;
                float bj = bp[c];
                #pragma unroll
                for (int r = 0; r < 4; r++) {
                    int r_g = row0 + wm * 64 + i * 16 + quad * 4 + r;
                    op[(size_t)r_g * 1024 + c] = f2bf((acc[i][j][r] + bj) * scl);
                }
            }
    } else {
        #pragma unroll
        for (int i = 0; i < 4; i++)
            #pragma unroll
            for (int j = 0; j < 4; j++) {
                int c_g = n0g + wn * 64 + j * 16 + l16;
                float bj = b0[c_g];
                #pragma unroll
                for (int r = 0; r < 4; r++) {
                    int r_g = row0 + wm * 64 + i * 16 + quad * 4 + r;
                    size_t idx = (size_t)r_g * 1024 + c_g;
                    outQ[idx] = f2bf(acc[i][j][r] + bj + resid[idx]);
                }
            }
    }
}

// Causal flash attention, S^T formulation, in-register P (no Pt LDS).
// R14-FROZEN: 64-row Q blocks, 4 waves x 16 q-rows, Kt+Vt LDS with
// register-prefetch dbuf, y->qb balance permutation (34 tiles/CU class).
// P redistribution quad-exchange (verified R11/R12):
//   cvt_pk_bf16 pairs (E from even c, O from odd c), then
//   permlane32_swap + permlane16_swap: (E0,O0)->(word0,word2),
//   (E1,O1)->(word1,word3).
__global__ __launch_bounds__(256, 4) void flash_kernel(
    const unsigned short* __restrict__ Q,
    const unsigned short* __restrict__ K,
    const unsigned short* __restrict__ VT,
    unsigned short* __restrict__ Ctx)
{
    __shared__ __align__(16) unsigned short Kt[128 * 72];    // [kpos][dk]
    __shared__ __align__(16) unsigned short Vt[64 * 136];    // [dv][kpos]
    const int tid = threadIdx.x;
    const int lane = tid & 63, wave = tid >> 6;
    const int quad = lane >> 4, l16 = lane & 15;
    const int y = blockIdx.y;
    const int qb = (y < 8) ? (31 - y) : (y < 16) ? (y - 8)
                 : (y < 24) ? (39 - y) : (y - 16);
    const int q0 = qb * 64;
    const long base = (long)blockIdx.x * 131072;
    const int nt = (qb + 2) >> 1;

    bf16x8 qa[2];
    #pragma unroll
    for (int h = 0; h < 2; h++)
        qa[h] = *(const bf16x8*)(Q + base + (q0 + wave * 16 + l16) * 64 + h * 32 + quad * 8);

    f32x4 o[4] = {};
    float l_one = 0.f;
    const int qpos = q0 + wave * 16 + l16;

    // stage tile 0
    #pragma unroll
    for (int u = 0; u < 4; u++) {
        int e = u * 256 + tid;
        int r = e >> 3, c = (e & 7) * 8;
        *(ushort8*)(Kt + r * 72 + c) = *(const ushort8*)(K + base + (long)r * 64 + c);
        int dv = e >> 4, kc = (e & 15) * 8;
        *(ushort8*)(Vt + dv * 136 + kc) = *(const ushort8*)(VT + base + (long)dv * 2048 + kc);
    }
    __syncthreads();

    for (int t = 0; t < nt; t++) {
        ushort8 nk[4], nv[4];
        if (t + 1 < nt) {
            const int k1 = (t + 1) * 128;
            #pragma unroll
            for (int u = 0; u < 4; u++) {
                int e = u * 256 + tid;
                int r = e >> 3, c = (e & 7) * 8;
                nk[u] = *(const ushort8*)(K + base + (long)(k1 + r) * 64 + c);
                int dv = e >> 4, kc = (e & 15) * 8;
                nv[u] = *(const ushort8*)(VT + base + (long)dv * 2048 + k1 + kc);
            }
        }
        const int k0 = t * 128;
        const bool diag = (t == nt - 1);
        // wave w needs kpos up to q0+16w+15; pairs kk<=kkmax.
        const int kkmax = diag ? ((q0 - k0 + wave * 16 + 15) >> 5) : 3;

        #pragma unroll
        for (int kk = 0; kk < 4; kk++) {
            if (kk <= kkmax) {
                const int cE = kk * 2, cO = kk * 2 + 1;
                f32x4 aE = {}, aO = {};
                {
                    bf16x8 kb0 = *(const bf16x8*)(Kt + (cE * 16 + l16) * 72 + quad * 8);
                    bf16x8 kb1 = *(const bf16x8*)(Kt + (cE * 16 + l16) * 72 + 32 + quad * 8);
                    aE = __builtin_amdgcn_mfma_f32_16x16x32_bf16(kb0, qa[0], aE, 0, 0, 0);
                    aE = __builtin_amdgcn_mfma_f32_16x16x32_bf16(kb1, qa[1], aE, 0, 0, 0);
                }
                {
                    bf16x8 kb0 = *(const bf16x8*)(Kt + (cO * 16 + l16) * 72 + quad * 8);
                    bf16x8 kb1 = *(const bf16x8*)(Kt + (cO * 16 + l16) * 72 + 32 + quad * 8);
                    aO = __builtin_amdgcn_mfma_f32_16x16x32_bf16(kb0, qa[0], aO, 0, 0, 0);
                    aO = __builtin_amdgcn_mfma_f32_16x16x32_bf16(kb1, qa[1], aO, 0, 0, 0);
                }
                float pE[4], pO[4];
                #pragma unroll
                for (int r = 0; r < 4; r++) {
                    float e1 = __expf(aE[r]);
                    float e2 = __expf(aO[r]);
                    if (diag) {
                        int kE = k0 + cE * 16 + quad * 4 + r;
                        int kO = k0 + cO * 16 + quad * 4 + r;
                        e1 = (kE > qpos) ? 0.f : e1;
                        e2 = (kO > qpos) ? 0.f : e2;
                    }
                    pE[r] = e1; pO[r] = e2;
                }
                l_one += (pE[0] + pE[1]) + (pE[2] + pE[3])
                       + (pO[0] + pO[1]) + (pO[2] + pO[3]);
                unsigned w0 = cvt_pk_bf16(pE[0], pE[1]);   // E0
                unsigned w1 = cvt_pk_bf16(pE[2], pE[3]);   // E1
                unsigned w2 = cvt_pk_bf16(pO[0], pO[1]);   // O0
                unsigned w3 = cvt_pk_bf16(pO[2], pO[3]);   // O1
                // (E0,O0) -> word0/word2 ; (E1,O1) -> word1/word3
                asm("v_permlane32_swap_b32 %0, %1" : "+v"(w0), "+v"(w2));
                asm("v_permlane16_swap_b32 %0, %1" : "+v"(w0), "+v"(w2));
                asm("v_permlane32_swap_b32 %0, %1" : "+v"(w1), "+v"(w3));
                asm("v_permlane16_swap_b32 %0, %1" : "+v"(w1), "+v"(w3));
                u32x4 pu;
                pu[0] = w0; pu[1] = w1; pu[2] = w2; pu[3] = w3;
                bf16x8 pa = __builtin_bit_cast(bf16x8, pu);
                #pragma unroll
                for (int c2 = 0; c2 < 4; c2++) {
                    bf16x8 vb = *(const bf16x8*)(Vt + (c2 * 16 + l16) * 136 + kk * 32 + quad * 8);
                    o[c2] = __builtin_amdgcn_mfma_f32_16x16x32_bf16(pa, vb, o[c2], 0, 0, 0);
                }
            }
        }
        __syncthreads();
        if (t + 1 < nt) {
            #pragma unroll
            for (int u = 0; u < 4; u++) {
                int e = u * 256 + tid;
                int r = e >> 3, c = (e & 7) * 8;
                *(ushort8*)(Kt + r * 72 + c) = nk[u];
                int dv = e >> 4, kc = (e & 15) * 8;
                *(ushort8*)(Vt + dv * 136 + kc) = nv[u];
            }
            __syncthreads();
        }
    }

    l_one += __shfl_xor(l_one, 16, 64);
    l_one += __shfl_xor(l_one, 32, 64);
    float rinv[4];
    #pragma unroll
    for (int r = 0; r < 4; r++)
        rinv[r] = 1.0f / __shfl(l_one, quad * 4 + r, 16);
    #pragma unroll
    for (int c2 = 0; c2 < 4; c2++)
        #pragma unroll
        for (int r = 0; r < 4; r++) {
            int row = q0 + wave * 16 + quad * 4 + r;
            Ctx[base + (long)row * 64 + c2 * 16 + l16] = f2bf(o[c2][r] * rinv[r]);
        }
}

// LayerNorm over bf16 input rows (out-proj+resid already applied), fp32 out.
__global__ __launch_bounds__(256) void ln_kernel(const unsigned short* __restrict__ inp,
                                                 const float* __restrict__ gamma,
                                                 const float* __restrict__ beta,
                                                 float* __restrict__ out)
{
    __shared__ float ssum[4], ssq[4];
    const int row = blockIdx.x;
    const int tid = threadIdx.x;
    ushort4 uv = ((const ushort4*)(inp + (size_t)row * 1024))[tid];
    float vx = bf2f(uv.x), vy = bf2f(uv.y), vz = bf2f(uv.z), vw = bf2f(uv.w);
    float s = vx + vy + vz + vw;
    float q = vx * vx + vy * vy + vz * vz + vw * vw;
    #pragma unroll
    for (int off = 32; off >= 1; off >>= 1) {
        s += __shfl_xor(s, off, 64);
        q += __shfl_xor(q, off, 64);
    }
    if ((tid & 63) == 0) { ssum[tid >> 6] = s; ssq[tid >> 6] = q; }
    __syncthreads();
    float ts = ssum[0] + ssum[1] + ssum[2] + ssum[3];
    float tq = ssq[0] + ssq[1] + ssq[2] + ssq[3];
    float mean = ts * (1.f / 1024.f);
    float var = tq * (1.f / 1024.f) - mean * mean;
    float rinv = rsqrtf(var + 1e-5f);
    float4 g = ((const float4*)gamma)[tid];
    float4 b = ((const float4*)beta)[tid];
    float4 o;
    o.x = (vx - mean) * rinv * g.x + b.x;
    o.y = (vy - mean) * rinv * g.y + b.y;
    o.z = (vz - mean) * rinv * g.z + b.z;
    o.w = (vw - mean) * rinv * g.w + b.w;
    ((float4*)(out + (size_t)row * 1024))[tid] = o;
}

extern "C" void kernel_launch(void* const* d_in, const int* in_sizes, int n_in,
                              void* d_out, int out_size, void* d_ws, size_t ws_size,
                              hipStream_t stream) {
    const float* x     = (const float*)d_in[0];
    const float* Wk    = (const float*)d_in[1];
    const float* bk    = (const float*)d_in[2];
    const float* Wq    = (const float*)d_in[3];
    const float* bq    = (const float*)d_in[4];
    const float* Wv    = (const float*)d_in[5];
    const float* bv    = (const float*)d_in[6];
    const float* Wo    = (const float*)d_in[7];
    const float* bo    = (const float*)d_in[8];
    const float* gamma = (const float*)d_in[9];
    const float* beta  = (const float*)d_in[10];
    float* out = (float*)d_out;

    char* ws = (char*)d_ws;
    unsigned short* xb    = (unsigned short*)(ws);                 // 8 MB
    unsigned short* WqkvT = (unsigned short*)(ws + (8ull << 20));  // 8 MB (incl WoT at +6MB)
    unsigned short* Qb    = (unsigned short*)(ws + (16ull << 20)); // 8 MB
    unsigned short* Kb    = (unsigned short*)(ws + (24ull << 20)); // 8 MB
    unsigned short* VbT   = (unsigned short*)(ws + (32ull << 20)); // 8 MB
    unsigned short* Cb    = (unsigned short*)(ws + (40ull << 20)); // 8 MB
    unsigned short* outp  = (unsigned short*)(ws + (48ull << 20)); // 8 MB bf16
    unsigned short* WoT   = WqkvT + (3u << 20);
    unsigned short* Vbn   = Cb;  // V normal layout, dead before flash writes Cb

    dim3 pgrid(16, 16, 5);
    prep_kernel<<<pgrid, 256, 0, stream>>>(x, Wq, Wk, Wv, Wo, xb, WqkvT);

    dim3 qkvgrid(24, 32);
    gemm_kernel<<<qkvgrid, 256, 0, stream>>>(xb, WqkvT, bq, bk, bv,
                                             Qb, Kb, Vbn, nullptr, 0);

    dim3 vgrid(32, 32);
    vtrans_kernel<<<vgrid, 256, 0, stream>>>(Vbn, VbT);

    dim3 fgrid(32, 32);
    flash_kernel<<<fgrid, 256, 0, stream>>>(Qb, Kb, VbT, Cb);

    dim3 ogrid(8, 32);
    gemm_kernel<<<ogrid, 256, 0, stream>>>(Cb, WoT, bo, nullptr, nullptr,
                                           outp, nullptr, nullptr, x, 1);

    ln_kernel<<<4096, 256, 0, stream>>>(outp, gamma, beta, out);
}